// Round 1
// baseline (229.215 us; speedup 1.0000x reference)
//
#include <hip/hip_runtime.h>
#include <hip/hip_bf16.h>

// Problem constants
// B=8, N=256, D=128, E=32, H=4, HD=32
// Workspace layout (float offsets); total 1,409,280 floats = 5.64 MB
#define OFF_WQT 0
#define OFF_WKT 16384
#define OFF_WVT 32768
#define OFF_OWT 49152
#define OFF_GWT 65536
#define OFF_WKE 81920
#define OFF_WVE 86016
#define OFF_KB  90112
#define OFF_VB  90240
#define OFF_SC  90368
#define OFF_QS  98560
#define OFF_QE  360704
#define OFF_HA  622848
#define OFF_O   884992
#define OFF_K0  1147136   // bf16 region: 262144 bf16 (131072 float slots)
#define OFF_V0  1278208   // bf16 region

static __device__ __forceinline__ float bflo(unsigned int w){
  union { unsigned int u; float f; } x; x.u = w << 16; return x.f;
}
static __device__ __forceinline__ float bfhi(unsigned int w){
  union { unsigned int u; float f; } x; x.u = w & 0xffff0000u; return x.f;
}
static __device__ __forceinline__ unsigned short f2bf(float f){
  union { float f; unsigned int u; } x; x.f = f;
  unsigned int r = (x.u + 0x7fffu + ((x.u >> 16) & 1u)) >> 16;
  return (unsigned short)r;
}

// ---------------------------------------------------------------------------
// Kernel A: transposes + fused edge-projection matrices + biases
// grid 353 x 256
// ---------------------------------------------------------------------------
__global__ __launch_bounds__(256) void prep_kernel(
    const float* __restrict__ wq, const float* __restrict__ wk,
    const float* __restrict__ wv, const float* __restrict__ out_w,
    const float* __restrict__ gcn_w, const float* __restrict__ edge_w,
    const float* __restrict__ edge_b, const float* __restrict__ bk,
    const float* __restrict__ bv, float* __restrict__ ws)
{
  int blk = blockIdx.x, t = threadIdx.x;
  if (blk < 320) {
    // 5 transposes: dst[k*128+d] = src[d*128+k]
    int w = blk >> 6;
    int e0 = (blk & 63) * 256 + t;        // [0,16384)
    const float* src = (w==0) ? wq : (w==1) ? wk : (w==2) ? wv : (w==3) ? out_w : gcn_w;
    float* dst = ws + ((w==0) ? OFF_WQT : (w==1) ? OFF_WKT : (w==2) ? OFF_WVT
                      : (w==3) ? OFF_OWT : OFF_GWT);
    int k = e0 >> 7, d = e0 & 127;
    dst[e0] = src[d*128 + k];
  } else if (blk < 352) {
    // Wke = wk @ edge_w, Wve = wv @ edge_w   (each D x E = 4096 elems)
    int idx = blk - 320;
    int which = idx >> 4;                  // 0: Wke, 1: Wve
    int e0 = (idx & 15) * 256 + t;         // [0,4096)
    int d = e0 >> 5, e = e0 & 31;
    const float* W = which ? wv : wk;
    float acc = 0.f;
    #pragma unroll 4
    for (int k2 = 0; k2 < 128; ++k2) acc += W[d*128+k2] * edge_w[k2*32+e];
    ws[(which ? OFF_WVE : OFF_WKE) + e0] = acc;
  } else {
    // kbias = wk@edge_b + bk ; vbias = wv@edge_b + bv
    int d = t & 127;
    const float* W  = (t < 128) ? wk : wv;
    const float* bb = (t < 128) ? bk : bv;
    float acc = bb[d];
    #pragma unroll 4
    for (int k2 = 0; k2 < 128; ++k2) acc += W[d*128+k2] * edge_b[k2];
    ws[((t < 128) ? OFF_KB : OFF_VB) + d] = acc;
  }
}

// ---------------------------------------------------------------------------
// Kernel B: per-row projections: q_s (q/sqrt(HD)), K0/V0 (bf16), qe, sconst
// grid 256 x 256 (8 rows per block)
// ---------------------------------------------------------------------------
__global__ __launch_bounds__(256) void proj_kernel(
    const float* __restrict__ h, const float* __restrict__ bq,
    float* __restrict__ ws)
{
  __shared__ float part1[2][8][128];
  __shared__ float part2[2][8][128];
  __shared__ float part3[2][8][128];
  __shared__ float qrow[8*132];

  int t = threadIdx.x;
  int d = t & 127;
  int kh = __builtin_amdgcn_readfirstlane(t >> 7);
  int r0 = blockIdx.x * 8;

  const float* wqT = ws + OFF_WQT;
  const float* wkT = ws + OFF_WKT;
  const float* wvT = ws + OFF_WVT;

  float aq[8] = {0,0,0,0,0,0,0,0};
  float ak[8] = {0,0,0,0,0,0,0,0};
  float av[8] = {0,0,0,0,0,0,0,0};

  for (int kk = 0; kk < 64; ++kk) {
    int k = kh*64 + kk;
    float qw = wqT[k*128 + d];
    float kw = wkT[k*128 + d];
    float vw = wvT[k*128 + d];
    #pragma unroll
    for (int i = 0; i < 8; ++i) {
      float hv = h[(r0+i)*128 + k];    // block-uniform -> s_load
      aq[i] += qw * hv;
      ak[i] += kw * hv;
      av[i] += vw * hv;
    }
  }
  #pragma unroll
  for (int i = 0; i < 8; ++i) {
    part1[kh][i][d] = aq[i];
    part2[kh][i][d] = ak[i];
    part3[kh][i][d] = av[i];
  }
  __syncthreads();

  unsigned short* K0 = (unsigned short*)(ws + OFF_K0);
  unsigned short* V0 = (unsigned short*)(ws + OFF_V0);
  if (t < 128) {
    const float inv = 0.17677669529663687f;  // 1/sqrt(32)
    #pragma unroll
    for (int i = 0; i < 8; ++i) {
      float q  = (part1[0][i][d] + part1[1][i][d] + bq[d]) * inv;
      float k0 = part2[0][i][d] + part2[1][i][d];
      float v0 = part3[0][i][d] + part3[1][i][d];
      ws[OFF_QS + (r0+i)*128 + d] = q;
      qrow[i*132 + d] = q;
      K0[(r0+i)*128 + d] = f2bf(k0);
      V0[(r0+i)*128 + d] = f2bf(v0);
    }
  }
  __syncthreads();

  // qe[r][h*32+e] = sum_j q_s[h*32+j] * Wke[(h*32+j)*32+e]
  const float* Wke = ws + OFF_WKE;
  #pragma unroll
  for (int rep = 0; rep < 4; ++rep) {
    int flat = rep*256 + t;
    int i = flat >> 7, he = flat & 127;
    int hh = he >> 5, e = he & 31;
    float acc = 0.f;
    #pragma unroll
    for (int j = 0; j < 32; ++j)
      acc += Wke[(hh*32+j)*32 + e] * qrow[i*132 + hh*32 + j];
    ws[OFF_QE + (r0+i)*128 + he] = acc;
  }
  // sconst[r][h] = q_s_h . kbias_h
  if (t < 32) {
    int i = t >> 2, hh = t & 3;
    float acc = 0.f;
    #pragma unroll
    for (int j = 0; j < 32; ++j)
      acc += qrow[i*132 + hh*32 + j] * ws[OFF_KB + hh*32 + j];
    ws[OFF_SC + (r0+i)*4 + hh] = acc;
  }
}

// ---------------------------------------------------------------------------
// Kernel C: GCN aggregation  h_agg = (adj+I)@h / deg
// grid 256 x 256 (8 rows per block)
// ---------------------------------------------------------------------------
__global__ __launch_bounds__(256) void gcn_kernel(
    const float* __restrict__ h, const float* __restrict__ adj,
    float* __restrict__ ws)
{
  __shared__ float part[2][8][128];
  __shared__ float dpart[2][8];

  int t = threadIdx.x;
  int d = t & 127;
  int mh = __builtin_amdgcn_readfirstlane(t >> 7);
  int b = blockIdx.x >> 5;
  int n0 = (blockIdx.x & 31) * 8;

  float acc[8] = {0,0,0,0,0,0,0,0};
  float deg[8] = {0,0,0,0,0,0,0,0};
  for (int mm = 0; mm < 128; ++mm) {
    int m = mh*128 + mm;
    float hv = h[(b*256 + m)*128 + d];
    #pragma unroll
    for (int i = 0; i < 8; ++i) {
      float a = adj[(b*256 + n0 + i)*256 + m] + ((m == n0 + i) ? 1.0f : 0.0f);
      acc[i] += a * hv;
      deg[i] += a;
    }
  }
  #pragma unroll
  for (int i = 0; i < 8; ++i) part[mh][i][d] = acc[i];
  if (d == 0) {
    #pragma unroll
    for (int i = 0; i < 8; ++i) dpart[mh][i] = deg[i];
  }
  __syncthreads();
  if (t < 128) {
    #pragma unroll
    for (int i = 0; i < 8; ++i) {
      float s  = part[0][i][d] + part[1][i][d];
      float dg = dpart[0][i] + dpart[1][i];
      ws[OFF_HA + (b*256 + n0 + i)*128 + d] = s / dg;
    }
  }
}

// ---------------------------------------------------------------------------
// Kernel M: fused attention per (b,n). The HBM-heavy kernel.
// grid 2048 x 256
// ---------------------------------------------------------------------------
__global__ __launch_bounds__(256) void attn_kernel(
    const float* __restrict__ edge, const float* __restrict__ adj,
    const float* __restrict__ srcm, const float* __restrict__ ws,
    float* __restrict__ obuf)
{
  __shared__ float e_lds[256*36];     // padded rows (36 floats): b128 reads 2-way
  __shared__ float s_lds[4*264];      // scores -> attn (stride 264 breaks conflicts)
  __shared__ float red[8];            // max[4], 1/sum[4]
  __shared__ float part[16*132];      // partial buffers (reused)
  __shared__ float ebar[128];         // ebar[h][e]

  int t  = threadIdx.x;
  int bn = blockIdx.x;
  int b  = bn >> 8;

  const float* qs = ws + OFF_QS + (size_t)bn*128;   // uniform -> s_load
  const float* qe = ws + OFF_QE + (size_t)bn*128;
  const float* sc = ws + OFF_SC + (size_t)bn*4;
  const unsigned short* K0 = (const unsigned short*)(ws + OFF_K0);
  const unsigned short* V0 = (const unsigned short*)(ws + OFF_V0);

  // ---- Phase 1: thread m = t. Load e row -> regs + LDS; compute scores. ----
  int m = t;
  float4 ev[8];
  {
    const float4* ep = (const float4*)(edge + ((size_t)bn*256 + (size_t)m)*32);
    #pragma unroll
    for (int j = 0; j < 8; ++j) ev[j] = ep[j];
    float* erow = e_lds + m*36;
    #pragma unroll
    for (int j = 0; j < 8; ++j) ((float4*)erow)[j] = ev[j];
  }

  float s4[4];
  {
    const uint4* kv = (const uint4*)(K0 + (size_t)(b*256 + m)*128);
    #pragma unroll
    for (int hh = 0; hh < 4; ++hh) {
      float acc = sc[hh];
      #pragma unroll
      for (int q4 = 0; q4 < 4; ++q4) {
        uint4 kw = kv[hh*4 + q4];
        const float* qp = qs + hh*32 + q4*8;
        acc += qp[0]*bflo(kw.x) + qp[1]*bfhi(kw.x)
             + qp[2]*bflo(kw.y) + qp[3]*bfhi(kw.y)
             + qp[4]*bflo(kw.z) + qp[5]*bfhi(kw.z)
             + qp[6]*bflo(kw.w) + qp[7]*bfhi(kw.w);
      }
      const float* qep = qe + hh*32;
      #pragma unroll
      for (int j = 0; j < 8; ++j) {
        acc += qep[4*j+0]*ev[j].x + qep[4*j+1]*ev[j].y
             + qep[4*j+2]*ev[j].z + qep[4*j+3]*ev[j].w;
      }
      s4[hh] = acc;
    }
    float ma = adj[(size_t)bn*256 + m];
    float ms = srcm[(size_t)bn*256 + m];
    if (ma * ms == 0.0f) { s4[0] = s4[1] = s4[2] = s4[3] = -1e30f; }
    #pragma unroll
    for (int hh = 0; hh < 4; ++hh) s_lds[hh*264 + m] = s4[hh];
  }
  __syncthreads();

  // ---- Phase 2: per-head softmax stats (wave w handles head w) ----
  {
    int wvh = t >> 6, ln = t & 63;
    float v0 = s_lds[wvh*264 + ln];
    float v1 = s_lds[wvh*264 + ln + 64];
    float v2 = s_lds[wvh*264 + ln + 128];
    float v3 = s_lds[wvh*264 + ln + 192];
    float mx = fmaxf(fmaxf(v0, v1), fmaxf(v2, v3));
    #pragma unroll
    for (int off = 32; off > 0; off >>= 1) mx = fmaxf(mx, __shfl_down(mx, off));
    mx = __shfl(mx, 0);
    float sm = __expf(v0-mx) + __expf(v1-mx) + __expf(v2-mx) + __expf(v3-mx);
    #pragma unroll
    for (int off = 32; off > 0; off >>= 1) sm += __shfl_down(sm, off);
    if (ln == 0) { red[wvh] = mx; red[4+wvh] = 1.0f / sm; }
  }
  __syncthreads();

  // ---- Phase 3: attn weights back into s_lds ----
  {
    #pragma unroll
    for (int hh = 0; hh < 4; ++hh) {
      float a = __expf(s4[hh] - red[hh]) * red[4+hh];
      s_lds[hh*264 + m] = a;
    }
  }
  __syncthreads();

  // ---- Phase 4: ebar[h][:] = sum_m a[h][m] * e[m][:] ----
  {
    int ms = t >> 5, hh = (t >> 3) & 3, e4 = t & 7;
    float4 acc = {0,0,0,0};
    for (int jm = 0; jm < 32; ++jm) {
      int mm = ms*32 + jm;
      float a = s_lds[hh*264 + mm];
      float4 evv = *(const float4*)(e_lds + mm*36 + e4*4);
      acc.x += a*evv.x; acc.y += a*evv.y; acc.z += a*evv.z; acc.w += a*evv.w;
    }
    *(float4*)(part + ms*132 + hh*32 + e4*4) = acc;
  }
  __syncthreads();
  if (t < 128) {
    float s2 = 0.f;
    #pragma unroll
    for (int ms = 0; ms < 8; ++ms) s2 += part[ms*132 + t];
    ebar[t] = s2;
  }
  __syncthreads();

  // ---- Phase 5: o_pre[h][d] = sum_m a[h][m] * V0[b][m][h*32+d] ----
  {
    int ms = t >> 4, hh = (t >> 2) & 3, dg = t & 3;
    float a0=0,a1=0,a2=0,a3=0,a4=0,a5=0,a6=0,a7=0;
    const uint4* vb = (const uint4*)(V0 + (size_t)b*256*128);
    int colq = hh*4 + dg;
    for (int jm = 0; jm < 16; ++jm) {
      int mm = ms*16 + jm;
      float a = s_lds[hh*264 + mm];
      uint4 vw = vb[mm*16 + colq];
      a0 += a*bflo(vw.x); a1 += a*bfhi(vw.x);
      a2 += a*bflo(vw.y); a3 += a*bfhi(vw.y);
      a4 += a*bflo(vw.z); a5 += a*bfhi(vw.z);
      a6 += a*bflo(vw.w); a7 += a*bfhi(vw.w);
    }
    float* pp = part + ms*132 + hh*32 + dg*8;
    pp[0]=a0; pp[1]=a1; pp[2]=a2; pp[3]=a3; pp[4]=a4; pp[5]=a5; pp[6]=a6; pp[7]=a7;
  }
  __syncthreads();

  // ---- Phase 6: o = o_pre + Wve@ebar + vbias ----
  if (t < 128) {
    float s2 = 0.f;
    #pragma unroll
    for (int ms = 0; ms < 16; ++ms) s2 += part[ms*132 + t];
    int hh = t >> 5;
    float acc = s2 + ws[OFF_VB + t];
    const float* wve = ws + OFF_WVE + t*32;
    #pragma unroll
    for (int e = 0; e < 32; ++e) acc += wve[e] * ebar[hh*32 + e];
    obuf[(size_t)bn*128 + t] = acc;
  }
}

// ---------------------------------------------------------------------------
// Kernel D: out = LN(h + o@out_w^T + out_b) + h_agg@gcn_w^T + gcn_b
// grid 256 x 256 (8 rows per block)
// ---------------------------------------------------------------------------
__global__ __launch_bounds__(256) void final_kernel(
    const float* __restrict__ h, const float* __restrict__ ws,
    const float* __restrict__ out_b, const float* __restrict__ ln_g,
    const float* __restrict__ ln_b, const float* __restrict__ gcn_b,
    float* __restrict__ out)
{
  __shared__ float p1[2][8][128];
  __shared__ float p2[2][8][128];
  __shared__ float xl[8*132];
  __shared__ float stat[16];

  int t = threadIdx.x;
  int d = t & 127;
  int kh = __builtin_amdgcn_readfirstlane(t >> 7);
  int r0 = blockIdx.x * 8;

  const float* owT = ws + OFF_OWT;
  const float* gwT = ws + OFF_GWT;
  const float* ob  = ws + OFF_O;
  const float* ha  = ws + OFF_HA;

  float xa[8] = {0,0,0,0,0,0,0,0};
  float ga[8] = {0,0,0,0,0,0,0,0};
  for (int kk = 0; kk < 64; ++kk) {
    int k = kh*64 + kk;
    float ow = owT[k*128 + d];
    float gw = gwT[k*128 + d];
    #pragma unroll
    for (int i = 0; i < 8; ++i) {
      xa[i] += ow * ob[(r0+i)*128 + k];   // uniform -> s_load
      ga[i] += gw * ha[(r0+i)*128 + k];
    }
  }
  #pragma unroll
  for (int i = 0; i < 8; ++i) { p1[kh][i][d] = xa[i]; p2[kh][i][d] = ga[i]; }
  __syncthreads();

  float gtot[8];
  if (t < 128) {
    #pragma unroll
    for (int i = 0; i < 8; ++i) {
      float x = p1[0][i][d] + p1[1][i][d] + out_b[d] + h[(r0+i)*128 + d];
      xl[i*132 + d] = x;
      gtot[i] = p2[0][i][d] + p2[1][i][d];
    }
  }
  __syncthreads();

  {
    int i = t >> 5, l = t & 31;
    float s = 0.f, ss = 0.f;
    #pragma unroll
    for (int j = 0; j < 4; ++j) {
      float x = xl[i*132 + l + 32*j];
      s += x; ss += x*x;
    }
    #pragma unroll
    for (int off = 16; off > 0; off >>= 1) {
      s  += __shfl_down(s,  off, 32);
      ss += __shfl_down(ss, off, 32);
    }
    if (l == 0) {
      float mu  = s * (1.0f/128.0f);
      float var = ss * (1.0f/128.0f) - mu*mu;
      stat[i]   = mu;
      stat[8+i] = rsqrtf(var + 1e-5f);
    }
  }
  __syncthreads();

  if (t < 128) {
    #pragma unroll
    for (int i = 0; i < 8; ++i) {
      float mu = stat[i], rs = stat[8+i];
      float x  = xl[i*132 + d];
      out[(r0+i)*128 + d] = ln_g[d]*(x-mu)*rs + ln_b[d] + gtot[i] + gcn_b[d];
    }
  }
}

// ---------------------------------------------------------------------------
extern "C" void kernel_launch(void* const* d_in, const int* in_sizes, int n_in,
                              void* d_out, int out_size, void* d_ws, size_t ws_size,
                              hipStream_t stream) {
  (void)in_sizes; (void)n_in; (void)out_size; (void)ws_size;
  const float* h     = (const float*)d_in[0];
  const float* adj   = (const float*)d_in[1];
  const float* edge  = (const float*)d_in[2];
  const float* srcm  = (const float*)d_in[3];
  // gcn_w=4, gcn_b=5, edge_w=6, edge_b=7, wq=8, wk=9, wv=10, bq=11, bk=12,
  // bv=13, out_w=14, out_b=15, ln_g=16, ln_b=17
  const float* gcn_w = (const float*)d_in[4];
  const float* gcn_b = (const float*)d_in[5];
  const float* edge_w= (const float*)d_in[6];
  const float* edge_b= (const float*)d_in[7];
  const float* wq    = (const float*)d_in[8];
  const float* wk    = (const float*)d_in[9];
  const float* wv    = (const float*)d_in[10];
  const float* bq    = (const float*)d_in[11];
  const float* bk    = (const float*)d_in[12];
  const float* bv    = (const float*)d_in[13];
  const float* out_w = (const float*)d_in[14];
  const float* out_b = (const float*)d_in[15];
  const float* ln_g  = (const float*)d_in[16];
  const float* ln_b  = (const float*)d_in[17];

  float* ws  = (float*)d_ws;   // needs >= 5.64 MB
  float* out = (float*)d_out;

  prep_kernel<<<353, 256, 0, stream>>>(wq, wk, wv, out_w, gcn_w, edge_w, edge_b, bk, bv, ws);
  proj_kernel<<<256, 256, 0, stream>>>(h, bq, ws);
  gcn_kernel<<<256, 256, 0, stream>>>(h, adj, ws);
  attn_kernel<<<2048, 256, 0, stream>>>(edge, adj, srcm, ws, ws + OFF_O);
  final_kernel<<<256, 256, 0, stream>>>(h, ws, out_b, ln_g, ln_b, gcn_b, out);
}

// Round 2
// 197.501 us; speedup vs baseline: 1.1606x; 1.1606x over previous
//
#include <hip/hip_runtime.h>
#include <hip/hip_bf16.h>

// B=8, N=256, D=128, E=32, H=4, HD=32
// Workspace layout (float offsets)
#define OFF_WQT 0
#define OFF_WKT 16384
#define OFF_WVT 32768
#define OFF_OWT 49152
#define OFF_GWT 65536
#define OFF_WKE 81920
#define OFF_WVE 86016
#define OFF_KB  90112
#define OFF_VB  90240
#define OFF_SC  90368
#define OFF_QS  98560
#define OFF_QE  360704
#define OFF_O   884992
#define OFF_K0  1147136   // bf16 region: 262144 bf16
#define OFF_V0  1278208   // bf16 region

static __device__ __forceinline__ float bflo(unsigned int w){
  union { unsigned int u; float f; } x; x.u = w << 16; return x.f;
}
static __device__ __forceinline__ float bfhi(unsigned int w){
  union { unsigned int u; float f; } x; x.u = w & 0xffff0000u; return x.f;
}
static __device__ __forceinline__ unsigned short f2bf(float f){
  union { float f; unsigned int u; } x; x.f = f;
  unsigned int r = (x.u + 0x7fffu + ((x.u >> 16) & 1u)) >> 16;
  return (unsigned short)r;
}

// ---------------------------------------------------------------------------
// Kernel A: transposes + fused edge-projection matrices + biases (tiny)
// ---------------------------------------------------------------------------
__global__ __launch_bounds__(256) void prep_kernel(
    const float* __restrict__ wq, const float* __restrict__ wk,
    const float* __restrict__ wv, const float* __restrict__ out_w,
    const float* __restrict__ gcn_w, const float* __restrict__ edge_w,
    const float* __restrict__ edge_b, const float* __restrict__ bk,
    const float* __restrict__ bv, float* __restrict__ ws)
{
  int blk = blockIdx.x, t = threadIdx.x;
  if (blk < 320) {
    int w = blk >> 6;
    int e0 = (blk & 63) * 256 + t;
    const float* src = (w==0) ? wq : (w==1) ? wk : (w==2) ? wv : (w==3) ? out_w : gcn_w;
    float* dst = ws + ((w==0) ? OFF_WQT : (w==1) ? OFF_WKT : (w==2) ? OFF_WVT
                      : (w==3) ? OFF_OWT : OFF_GWT);
    int k = e0 >> 7, d = e0 & 127;
    dst[e0] = src[d*128 + k];
  } else if (blk < 352) {
    int idx = blk - 320;
    int which = idx >> 4;
    int e0 = (idx & 15) * 256 + t;
    int d = e0 >> 5, e = e0 & 31;
    const float* W = which ? wv : wk;
    float acc = 0.f;
    #pragma unroll 4
    for (int k2 = 0; k2 < 128; ++k2) acc += W[d*128+k2] * edge_w[k2*32+e];
    ws[(which ? OFF_WVE : OFF_WKE) + e0] = acc;
  } else {
    int d = t & 127;
    const float* W  = (t < 128) ? wk : wv;
    const float* bb = (t < 128) ? bk : bv;
    float acc = bb[d];
    #pragma unroll 4
    for (int k2 = 0; k2 < 128; ++k2) acc += W[d*128+k2] * edge_b[k2];
    ws[((t < 128) ? OFF_KB : OFF_VB) + d] = acc;
  }
}

// ---------------------------------------------------------------------------
// Kernel B: per-row projections. 4 rows/block, grid 512 (2 blocks/CU).
// h staged to LDS via coalesced float4 (no scalar-load chains).
// ---------------------------------------------------------------------------
__global__ __launch_bounds__(256) void proj_kernel(
    const float* __restrict__ h, const float* __restrict__ bq,
    float* __restrict__ ws)
{
  __shared__ float h_lds[512];            // 4 rows x 128
  __shared__ float p1[2][4][128];
  __shared__ float p2[2][4][128];
  __shared__ float p3[2][4][128];
  __shared__ float qrow[4*132];

  int t = threadIdx.x;
  int d = t & 127;
  int kh = t >> 7;
  int r0 = blockIdx.x * 4;

  if (t < 128) ((float4*)h_lds)[t] = ((const float4*)(h + (size_t)r0*128))[t];
  __syncthreads();

  const float* wqT = ws + OFF_WQT;
  const float* wkT = ws + OFF_WKT;
  const float* wvT = ws + OFF_WVT;

  float aq[4] = {0,0,0,0};
  float ak[4] = {0,0,0,0};
  float av[4] = {0,0,0,0};

  for (int kk = 0; kk < 64; ++kk) {
    int k = kh*64 + kk;
    float qw = wqT[k*128 + d];
    float kw = wkT[k*128 + d];
    float vw = wvT[k*128 + d];
    #pragma unroll
    for (int i = 0; i < 4; ++i) {
      float hv = h_lds[i*128 + k];        // wave-uniform -> broadcast
      aq[i] += qw * hv;
      ak[i] += kw * hv;
      av[i] += vw * hv;
    }
  }
  #pragma unroll
  for (int i = 0; i < 4; ++i) {
    p1[kh][i][d] = aq[i];
    p2[kh][i][d] = ak[i];
    p3[kh][i][d] = av[i];
  }
  __syncthreads();

  unsigned short* K0 = (unsigned short*)(ws + OFF_K0);
  unsigned short* V0 = (unsigned short*)(ws + OFF_V0);
  if (t < 128) {
    const float inv = 0.17677669529663687f;  // 1/sqrt(32)
    #pragma unroll
    for (int i = 0; i < 4; ++i) {
      float q  = (p1[0][i][d] + p1[1][i][d] + bq[d]) * inv;
      float k0 = p2[0][i][d] + p2[1][i][d];
      float v0 = p3[0][i][d] + p3[1][i][d];
      ws[OFF_QS + (size_t)(r0+i)*128 + d] = q;
      qrow[i*132 + d] = q;
      K0[(size_t)(r0+i)*128 + d] = f2bf(k0);
      V0[(size_t)(r0+i)*128 + d] = f2bf(v0);
    }
  }
  __syncthreads();

  // qe[r][h*32+e] = sum_j q_s[h*32+j] * Wke[(h*32+j)*32+e]
  const float* Wke = ws + OFF_WKE;
  #pragma unroll
  for (int rep = 0; rep < 2; ++rep) {
    int flat = rep*256 + t;
    int i = flat >> 7, he = flat & 127;
    int hh = he >> 5, e = he & 31;
    float acc = 0.f;
    #pragma unroll
    for (int j = 0; j < 32; ++j)
      acc += Wke[(hh*32+j)*32 + e] * qrow[i*132 + hh*32 + j];
    ws[OFF_QE + (size_t)(r0+i)*128 + he] = acc;
  }
  // sconst[r][h] = q_s_h . kbias_h
  if (t < 16) {
    int i = t >> 2, hh = t & 3;
    float acc = 0.f;
    #pragma unroll
    for (int j = 0; j < 32; ++j)
      acc += qrow[i*132 + hh*32 + j] * ws[OFF_KB + hh*32 + j];
    ws[OFF_SC + (size_t)(r0+i)*4 + hh] = acc;
  }
}

// ---------------------------------------------------------------------------
// Kernel M: fused attention per (b,n). LDS 31.5 KB -> 5 blocks/CU.
// ---------------------------------------------------------------------------
__global__ __launch_bounds__(256, 4) void attn_kernel(
    const float* __restrict__ edge, const float* __restrict__ adj,
    const float* __restrict__ srcm, const float* __restrict__ ws,
    float* __restrict__ obuf)
{
  __shared__ unsigned int e_bf[256*18];   // bf16-packed edge rows, stride 18 uints
  __shared__ float s_lds[1028];           // 4 heads x stride 257
  __shared__ float part4[8*132];          // ebar partials
  __shared__ float part5[8*132];          // o partials
  __shared__ float ebar[128];
  __shared__ float red[8];

  int t  = threadIdx.x;
  int bn = blockIdx.x;
  int b  = bn >> 8;

  const float* qs = ws + OFF_QS + (size_t)bn*128;   // uniform -> s_load
  const float* qe = ws + OFF_QE + (size_t)bn*128;
  const float* sc = ws + OFF_SC + (size_t)bn*4;
  const unsigned short* K0 = (const unsigned short*)(ws + OFF_K0);
  const unsigned int*  V0u = (const unsigned int*)(ws + OFF_V0);

  // ---- Phase 1: thread m = t. e row -> regs (+bf16 LDS copy); scores. ----
  int m = t;
  float ma = adj[(size_t)bn*256 + m];
  float msk = srcm[(size_t)bn*256 + m];
  float4 ev[8];
  {
    const float4* ep = (const float4*)(edge + ((size_t)bn*256 + (size_t)m)*32);
    #pragma unroll
    for (int j = 0; j < 8; ++j) ev[j] = ep[j];
    unsigned int* erow = e_bf + m*18;
    #pragma unroll
    for (int j = 0; j < 8; ++j) {
      uint2 pk;
      pk.x = (unsigned int)f2bf(ev[j].x) | ((unsigned int)f2bf(ev[j].y) << 16);
      pk.y = (unsigned int)f2bf(ev[j].z) | ((unsigned int)f2bf(ev[j].w) << 16);
      *(uint2*)(erow + j*2) = pk;
    }
  }

  float s4[4];
  {
    const uint4* kv = (const uint4*)(K0 + (size_t)(b*256 + m)*128);
    #pragma unroll
    for (int hh = 0; hh < 4; ++hh) {
      float acc = sc[hh];
      #pragma unroll
      for (int q4 = 0; q4 < 4; ++q4) {
        uint4 kw = kv[hh*4 + q4];
        const float* qp = qs + hh*32 + q4*8;
        acc += qp[0]*bflo(kw.x) + qp[1]*bfhi(kw.x)
             + qp[2]*bflo(kw.y) + qp[3]*bfhi(kw.y)
             + qp[4]*bflo(kw.z) + qp[5]*bfhi(kw.z)
             + qp[6]*bflo(kw.w) + qp[7]*bfhi(kw.w);
      }
      const float* qep = qe + hh*32;
      #pragma unroll
      for (int j = 0; j < 8; ++j) {
        acc += qep[4*j+0]*ev[j].x + qep[4*j+1]*ev[j].y
             + qep[4*j+2]*ev[j].z + qep[4*j+3]*ev[j].w;
      }
      s4[hh] = acc;
    }
    if (ma * msk == 0.0f) { s4[0] = s4[1] = s4[2] = s4[3] = -1e30f; }
    #pragma unroll
    for (int hh = 0; hh < 4; ++hh) s_lds[hh*257 + m] = s4[hh];
  }
  __syncthreads();

  // ---- Phase 2: per-head softmax stats (wave w -> head w) ----
  {
    int wvh = t >> 6, ln = t & 63;
    float v0 = s_lds[wvh*257 + ln];
    float v1 = s_lds[wvh*257 + ln + 64];
    float v2 = s_lds[wvh*257 + ln + 128];
    float v3 = s_lds[wvh*257 + ln + 192];
    float mx = fmaxf(fmaxf(v0, v1), fmaxf(v2, v3));
    #pragma unroll
    for (int off = 32; off > 0; off >>= 1) mx = fmaxf(mx, __shfl_down(mx, off));
    mx = __shfl(mx, 0);
    float sm = __expf(v0-mx) + __expf(v1-mx) + __expf(v2-mx) + __expf(v3-mx);
    #pragma unroll
    for (int off = 32; off > 0; off >>= 1) sm += __shfl_down(sm, off);
    if (ln == 0) { red[wvh] = mx; red[4+wvh] = 1.0f / sm; }
  }
  __syncthreads();

  // ---- Phase 3: attn weights into s_lds ----
  #pragma unroll
  for (int hh = 0; hh < 4; ++hh)
    s_lds[hh*257 + m] = __expf(s4[hh] - red[hh]) * red[4+hh];
  __syncthreads();

  // ---- Phase 4+5 merged: ebar partials + o partials in one m-sweep ----
  {
    int ms  = t >> 5;
    int hh4 = (t >> 3) & 3, e4 = t & 7;
    int c   = t & 31,  hh5 = c >> 3;
    float p4x=0,p4y=0,p4z=0,p4w=0;
    float p5x=0,p5y=0,p5z=0,p5w=0;
    const unsigned int* vrow = V0u + (size_t)b*256*64;
    for (int jm = 0; jm < 32; ++jm) {
      int mm = ms*32 + jm;
      float a4 = s_lds[hh4*257 + mm];
      uint2 w = *(const uint2*)(e_bf + mm*18 + e4*2);
      p4x += a4*bflo(w.x); p4y += a4*bfhi(w.x);
      p4z += a4*bflo(w.y); p4w += a4*bfhi(w.y);
      float a5 = s_lds[hh5*257 + mm];
      uint2 vv = *(const uint2*)(vrow + (size_t)mm*64 + c*2);
      p5x += a5*bflo(vv.x); p5y += a5*bfhi(vv.x);
      p5z += a5*bflo(vv.y); p5w += a5*bfhi(vv.y);
    }
    float4 f4; f4.x=p4x; f4.y=p4y; f4.z=p4z; f4.w=p4w;
    *(float4*)(part4 + ms*132 + hh4*32 + e4*4) = f4;
    float4 f5; f5.x=p5x; f5.y=p5y; f5.z=p5z; f5.w=p5w;
    *(float4*)(part5 + ms*132 + c*4) = f5;
  }
  __syncthreads();

  // ---- Phase 6a: reduce partials ----
  float s2 = 0.f;
  if (t < 128) {
    float se = 0.f;
    #pragma unroll
    for (int g = 0; g < 8; ++g) { se += part4[g*132 + t]; s2 += part5[g*132 + t]; }
    ebar[t] = se;
  }
  __syncthreads();

  // ---- Phase 6b: o = o_pre + Wve@ebar + vbias ----
  if (t < 128) {
    int hh = t >> 5;
    float acc = s2 + ws[OFF_VB + t];
    const float* wve = ws + OFF_WVE + t*32;
    #pragma unroll
    for (int e = 0; e < 32; ++e) acc += wve[e] * ebar[hh*32 + e];
    obuf[(size_t)bn*128 + t] = acc;
  }
}

// ---------------------------------------------------------------------------
// Kernel D (fused GCN + final): h_agg, out-proj, residual+LN, gcn-proj, sum.
// 4 rows/block, grid 512.
// ---------------------------------------------------------------------------
__global__ __launch_bounds__(256) void final_kernel(
    const float* __restrict__ h, const float* __restrict__ adj,
    const float* __restrict__ ws, const float* __restrict__ out_b,
    const float* __restrict__ ln_g, const float* __restrict__ ln_b,
    const float* __restrict__ gcn_b, float* __restrict__ out)
{
  __shared__ float adj_lds[1024];   // 4 rows x 256
  __shared__ float o_lds[512];      // 4 rows x 128
  __shared__ float ha_lds[4*132];
  __shared__ float pa[2][4][128];
  __shared__ float pb[2][4][128];
  __shared__ float dpart[2][4];
  __shared__ float xl[4*132];
  __shared__ float stat[8];

  int t = threadIdx.x;
  int d = t & 127;
  int kh = t >> 7;
  int b  = blockIdx.x >> 6;
  int n0 = (blockIdx.x & 63) * 4;
  int r0 = b*256 + n0;

  ((float4*)adj_lds)[t] = ((const float4*)(adj + (size_t)r0*256))[t];
  if (t < 128) ((float4*)o_lds)[t] = ((const float4*)(ws + OFF_O + (size_t)r0*128))[t];
  __syncthreads();

  // --- GCN aggregation: h_agg rows (m-split across kh) ---
  {
    float ag[4] = {0,0,0,0};
    float dg[4] = {0,0,0,0};
    for (int mm = 0; mm < 128; ++mm) {
      int mloc = kh*128 + mm;
      float hv = h[((size_t)b*256 + mloc)*128 + d];
      #pragma unroll
      for (int i = 0; i < 4; ++i) {
        float a = adj_lds[i*256 + mloc] + ((mloc == n0 + i) ? 1.0f : 0.0f);
        ag[i] += a * hv;
        dg[i] += a;
      }
    }
    #pragma unroll
    for (int i = 0; i < 4; ++i) pa[kh][i][d] = ag[i];
    if (d == 0) {
      #pragma unroll
      for (int i = 0; i < 4; ++i) dpart[kh][i] = dg[i];
    }
  }
  __syncthreads();
  if (t < 128) {
    #pragma unroll
    for (int i = 0; i < 4; ++i)
      ha_lds[i*132 + d] = (pa[0][i][d] + pa[1][i][d]) / (dpart[0][i] + dpart[1][i]);
  }
  __syncthreads();

  // --- both matvecs: x = o@out_w^T, g = h_agg@gcn_w^T ---
  {
    const float* owT = ws + OFF_OWT;
    const float* gwT = ws + OFF_GWT;
    float xa[4] = {0,0,0,0};
    float ga[4] = {0,0,0,0};
    for (int kk = 0; kk < 64; ++kk) {
      int k = kh*64 + kk;
      float ow = owT[k*128 + d];
      float gw = gwT[k*128 + d];
      #pragma unroll
      for (int i = 0; i < 4; ++i) {
        xa[i] += ow * o_lds[i*128 + k];
        ga[i] += gw * ha_lds[i*132 + k];
      }
    }
    #pragma unroll
    for (int i = 0; i < 4; ++i) { pa[kh][i][d] = xa[i]; pb[kh][i][d] = ga[i]; }
  }
  __syncthreads();

  float gtot[4];
  if (t < 128) {
    #pragma unroll
    for (int i = 0; i < 4; ++i) {
      float x = pa[0][i][d] + pa[1][i][d] + out_b[d] + h[(size_t)(r0+i)*128 + d];
      xl[i*132 + d] = x;
      gtot[i] = pb[0][i][d] + pb[1][i][d];
    }
  }
  __syncthreads();

  // --- LayerNorm stats: row i reduced by 64 lanes ---
  {
    int i = t >> 6, l = t & 63;
    float x0 = xl[i*132 + l];
    float x1 = xl[i*132 + l + 64];
    float s = x0 + x1, ss = x0*x0 + x1*x1;
    #pragma unroll
    for (int off = 32; off > 0; off >>= 1) {
      s  += __shfl_down(s,  off);
      ss += __shfl_down(ss, off);
    }
    if (l == 0) {
      float mu  = s * (1.0f/128.0f);
      float var = ss * (1.0f/128.0f) - mu*mu;
      stat[i]   = mu;
      stat[4+i] = rsqrtf(var + 1e-5f);
    }
  }
  __syncthreads();

  if (t < 128) {
    #pragma unroll
    for (int i = 0; i < 4; ++i) {
      float x = xl[i*132 + d];
      out[(size_t)(r0+i)*128 + d] =
          ln_g[d]*(x - stat[i])*stat[4+i] + ln_b[d] + gtot[i] + gcn_b[d];
    }
  }
}

// ---------------------------------------------------------------------------
extern "C" void kernel_launch(void* const* d_in, const int* in_sizes, int n_in,
                              void* d_out, int out_size, void* d_ws, size_t ws_size,
                              hipStream_t stream) {
  (void)in_sizes; (void)n_in; (void)out_size; (void)ws_size;
  const float* h     = (const float*)d_in[0];
  const float* adj   = (const float*)d_in[1];
  const float* edge  = (const float*)d_in[2];
  const float* srcm  = (const float*)d_in[3];
  const float* gcn_w = (const float*)d_in[4];
  const float* gcn_b = (const float*)d_in[5];
  const float* edge_w= (const float*)d_in[6];
  const float* edge_b= (const float*)d_in[7];
  const float* wq    = (const float*)d_in[8];
  const float* wk    = (const float*)d_in[9];
  const float* wv    = (const float*)d_in[10];
  const float* bq    = (const float*)d_in[11];
  const float* bk    = (const float*)d_in[12];
  const float* bv    = (const float*)d_in[13];
  const float* out_w = (const float*)d_in[14];
  const float* out_b = (const float*)d_in[15];
  const float* ln_g  = (const float*)d_in[16];
  const float* ln_b  = (const float*)d_in[17];

  float* ws  = (float*)d_ws;   // needs >= 5.64 MB
  float* out = (float*)d_out;

  prep_kernel<<<353, 256, 0, stream>>>(wq, wk, wv, out_w, gcn_w, edge_w, edge_b, bk, bv, ws);
  proj_kernel<<<512, 256, 0, stream>>>(h, bq, ws);
  attn_kernel<<<2048, 256, 0, stream>>>(edge, adj, srcm, ws, ws + OFF_O);
  final_kernel<<<512, 256, 0, stream>>>(h, adj, ws, out_b, ln_g, ln_b, gcn_b, out);
}